// Round 1
// baseline (85.936 us; speedup 1.0000x reference)
//
#include <hip/hip_runtime.h>
#include <hip/hip_bf16.h>

using bf16x8 = __attribute__((ext_vector_type(8))) short;
using f32x4  = __attribute__((ext_vector_type(4))) float;

__device__ __forceinline__ unsigned short f2bf(float x) {
    unsigned int u = __float_as_uint(x);
    return (unsigned short)((u + 0x7FFFu + ((u >> 16) & 1u)) >> 16);
}

// -------------------------------------------------------------------------
// K1: ccombo[n][c] = focal(logits[n][c]) + 0.5*(1 - <v_norm[n], te[c]>)
// grid 256 x block 256 ; block = 64 rows (4 waves x 16), all 91 classes (pad 96)
// -------------------------------------------------------------------------
__global__ __launch_bounds__(256)
void k_class_embed(const float* __restrict__ logits,   // [16384][91]
                   const float* __restrict__ embed,    // [16384][512]
                   const float* __restrict__ te,       // [91][512]
                   float* __restrict__ ccombo)         // [16384][96]
{
    constexpr int LROW = 264;                      // 256 + 8 pad (bf16 elems)
    __shared__ unsigned short te_s[96 * LROW];     // 50688 B

    const int tid  = threadIdx.x;
    const int lane = tid & 63;
    const int wv   = tid >> 6;
    const int r16  = lane & 15;    // A row / B col within 16x16 tile
    const int q    = lane >> 4;    // k-quarter (8 contiguous k elems)
    const int nbase = blockIdx.x * 64 + wv * 16;

    f32x4 acc[6];
#pragma unroll
    for (int j = 0; j < 6; ++j) acc[j] = (f32x4){0.f, 0.f, 0.f, 0.f};
    float sumsq = 0.f;

    for (int ch = 0; ch < 2; ++ch) {
        __syncthreads();
        // stage te[:, ch*256 .. +256) as bf16 (rows 91..95 zeroed)
        for (int i = tid; i < 96 * 64; i += 256) {
            const int r = i >> 6, c4 = i & 63;
            unsigned short h0 = 0, h1 = 0, h2 = 0, h3 = 0;
            if (r < 91) {
                const float4 v = *(const float4*)(te + (size_t)r * 512 + ch * 256 + c4 * 4);
                h0 = f2bf(v.x); h1 = f2bf(v.y); h2 = f2bf(v.z); h3 = f2bf(v.w);
            }
            unsigned short* p = &te_s[r * LROW + c4 * 4];
            p[0] = h0; p[1] = h1; p[2] = h2; p[3] = h3;
        }
        __syncthreads();

        const float* aptr = embed + (size_t)(nbase + r16) * 512 + ch * 256 + q * 8;
        float4 a0 = *(const float4*)(aptr);
        float4 a1 = *(const float4*)(aptr + 4);
#pragma unroll
        for (int ks = 0; ks < 8; ++ks) {
            float4 p0, p1;
            if (ks < 7) {
                p0 = *(const float4*)(aptr + (ks + 1) * 32);
                p1 = *(const float4*)(aptr + (ks + 1) * 32 + 4);
            }
            bf16x8 af;
            const float fv[8] = {a0.x, a0.y, a0.z, a0.w, a1.x, a1.y, a1.z, a1.w};
#pragma unroll
            for (int j = 0; j < 8; ++j) {
                sumsq += fv[j] * fv[j];
                af[j] = (short)f2bf(fv[j]);
            }
#pragma unroll
            for (int ct = 0; ct < 6; ++ct) {
                const bf16x8 bfr = *(const bf16x8*)&te_s[(ct * 16 + r16) * LROW + ks * 32 + q * 8];
                acc[ct] = __builtin_amdgcn_mfma_f32_16x16x32_bf16(af, bfr, acc[ct], 0, 0, 0);
            }
            if (ks < 7) { a0 = p0; a1 = p1; }
        }
    }

    // full row sumsq lives split across lanes {l, l^16, l^32, l^48}
    sumsq += __shfl_xor(sumsq, 16);
    sumsq += __shfl_xor(sumsq, 32);
    const float rnorm_own = rsqrtf(sumsq);     // rnorm for row r16 (lanes 0..15 authoritative)
    float rn[4];
#pragma unroll
    for (int j = 0; j < 4; ++j) rn[j] = __shfl(rnorm_own, q * 4 + j);

#pragma unroll
    for (int ct = 0; ct < 6; ++ct) {
        const int c = ct * 16 + r16;
        if (c < 91) {
#pragma unroll
            for (int j = 0; j < 4; ++j) {
                const int n   = nbase + q * 4 + j;          // C/D: row=(lane>>4)*4+reg
                const float dot = acc[ct][j] * rn[j];
                const float x = logits[(size_t)n * 91 + c];
                const float p = 1.f / (1.f + __expf(-x));
                const float pos = 0.25f * (1.f - p) * (1.f - p) * (-__logf(p + 1e-8f));
                const float neg = 0.75f * p * p * (-__logf(1.f - p + 1e-8f));
                ccombo[(size_t)n * 96 + c] = (pos - neg) + 0.5f * (1.f - dot);
            }
        }
    }
}

// -------------------------------------------------------------------------
// K2: out[n][m] = ccombo[n][id[m]] + L1(cxcywh) - GIoU(xyxy)
// grid 1024 x block 256 ; block = 16 n-rows x all 1600 m
// -------------------------------------------------------------------------
__device__ __forceinline__ float cost_one(
    float pcx, float pcy, float pw, float ph,
    float px0, float py0, float px1, float py1, float pa,
    float tcx, float tcy, float tw, float th,
    float tx0, float ty0, float tx1, float ty1, float ta, float cc)
{
    const float l1 = fabsf(pcx - tcx) + fabsf(pcy - tcy) + fabsf(pw - tw) + fabsf(ph - th);
    const float ix0 = fmaxf(px0, tx0), iy0 = fmaxf(py0, ty0);
    const float ix1 = fminf(px1, tx1), iy1 = fminf(py1, ty1);
    const float iw = fmaxf(ix1 - ix0, 0.f), ih = fmaxf(iy1 - iy0, 0.f);
    const float inter = iw * ih;
    const float uni = pa + ta - inter;
    const float ex0 = fminf(px0, tx0), ey0 = fminf(py0, ty0);
    const float ex1 = fmaxf(px1, tx1), ey1 = fmaxf(py1, ty1);
    const float ew = fmaxf(ex1 - ex0, 0.f), eh = fmaxf(ey1 - ey0, 0.f);
    const float ae = ew * eh;
    const float giou = __fdividef(inter, uni) - __fdividef(ae - uni, ae);
    return cc + l1 - giou;
}

__global__ __launch_bounds__(256)
void k_cost(const float* __restrict__ pboxes,   // [16384][4] cxcywh
            const float* __restrict__ tboxes,   // [1600][4]  cxcywh
            const int*   __restrict__ tids,     // [1600]
            const float* __restrict__ ccombo,   // [16384][96]
            float* __restrict__ out)            // [16384][1600]
{
    __shared__ float t_cx[1600], t_cy[1600], t_w[1600], t_h[1600];
    __shared__ float t_x0[1600], t_y0[1600], t_x1[1600], t_y1[1600];
    __shared__ unsigned short t_id[1600];
    __shared__ float cc_s[16 * 96];
    __shared__ float pn_s[16 * 12];

    const int tid = threadIdx.x;
    const int n0  = blockIdx.x * 16;

    for (int m = tid; m < 1600; m += 256) {
        const float4 b = *(const float4*)(tboxes + (size_t)m * 4);
        t_cx[m] = b.x; t_cy[m] = b.y; t_w[m] = b.z; t_h[m] = b.w;
        t_x0[m] = b.x - 0.5f * b.z; t_y0[m] = b.y - 0.5f * b.w;
        t_x1[m] = b.x + 0.5f * b.z; t_y1[m] = b.y + 0.5f * b.w;
        t_id[m] = (unsigned short)tids[m];
    }
    for (int i = tid; i < 16 * 96; i += 256)
        cc_s[i] = ccombo[(size_t)n0 * 96 + i];
    if (tid < 16) {
        const float4 b = *(const float4*)(pboxes + (size_t)(n0 + tid) * 4);
        float* p = &pn_s[tid * 12];
        p[0] = b.x; p[1] = b.y; p[2] = b.z; p[3] = b.w;
        p[4] = b.x - 0.5f * b.z; p[5] = b.y - 0.5f * b.w;
        p[6] = b.x + 0.5f * b.z; p[7] = b.y + 0.5f * b.w;
        p[8] = b.z * b.w;                       // area1
    }
    __syncthreads();

    for (int g = tid; g < 400; g += 256) {
        const int m0 = g * 4;
        const float4 mcx = *(const float4*)&t_cx[m0];
        const float4 mcy = *(const float4*)&t_cy[m0];
        const float4 mw  = *(const float4*)&t_w[m0];
        const float4 mh  = *(const float4*)&t_h[m0];
        const float4 mx0 = *(const float4*)&t_x0[m0];
        const float4 my0 = *(const float4*)&t_y0[m0];
        const float4 mx1 = *(const float4*)&t_x1[m0];
        const float4 my1 = *(const float4*)&t_y1[m0];
        const int id0 = t_id[m0], id1 = t_id[m0 + 1], id2 = t_id[m0 + 2], id3 = t_id[m0 + 3];
        const float ta0 = mw.x * mh.x, ta1 = mw.y * mh.y, ta2 = mw.z * mh.z, ta3 = mw.w * mh.w;

#pragma unroll 4
        for (int n = 0; n < 16; ++n) {
            const float* p = &pn_s[n * 12];
            const float pcx = p[0], pcy = p[1], pw = p[2], ph = p[3];
            const float px0 = p[4], py0 = p[5], px1 = p[6], py1 = p[7];
            const float pa  = p[8];
            const float cc0 = cc_s[n * 96 + id0];
            const float cc1 = cc_s[n * 96 + id1];
            const float cc2 = cc_s[n * 96 + id2];
            const float cc3 = cc_s[n * 96 + id3];
            float4 res;
            res.x = cost_one(pcx,pcy,pw,ph, px0,py0,px1,py1,pa,
                             mcx.x,mcy.x,mw.x,mh.x, mx0.x,my0.x,mx1.x,my1.x, ta0, cc0);
            res.y = cost_one(pcx,pcy,pw,ph, px0,py0,px1,py1,pa,
                             mcx.y,mcy.y,mw.y,mh.y, mx0.y,my0.y,mx1.y,my1.y, ta1, cc1);
            res.z = cost_one(pcx,pcy,pw,ph, px0,py0,px1,py1,pa,
                             mcx.z,mcy.z,mw.z,mh.z, mx0.z,my0.z,mx1.z,my1.z, ta2, cc2);
            res.w = cost_one(pcx,pcy,pw,ph, px0,py0,px1,py1,pa,
                             mcx.w,mcy.w,mw.w,mh.w, mx0.w,my0.w,mx1.w,my1.w, ta3, cc3);
            *(float4*)(out + (size_t)(n0 + n) * 1600 + m0) = res;
        }
    }
}

extern "C" void kernel_launch(void* const* d_in, const int* in_sizes, int n_in,
                              void* d_out, int out_size, void* d_ws, size_t ws_size,
                              hipStream_t stream) {
    const float* pred_logits = (const float*)d_in[0];   // [16,1024,91]
    const float* pred_boxes  = (const float*)d_in[1];   // [16,1024,4]
    const float* pred_embed  = (const float*)d_in[2];   // [16,1024,512]
    const float* text_emb    = (const float*)d_in[3];   // [91,512]
    const int*   tgt_ids     = (const int*)d_in[4];     // [1600]
    const float* tgt_bbox    = (const float*)d_in[5];   // [1600,4]
    float* out    = (float*)d_out;                      // [16384,1600]
    float* ccombo = (float*)d_ws;                       // [16384,96] f32 = 6.3 MB

    k_class_embed<<<256, 256, 0, stream>>>(pred_logits, pred_embed, text_emb, ccombo);
    k_cost<<<1024, 256, 0, stream>>>(pred_boxes, tgt_bbox, tgt_ids, ccombo, out);
}